// Round 11
// baseline (35.209 us; speedup 1.0000x reference)
//
#include <hip/hip_runtime.h>
#include <stdint.h>

typedef unsigned int u32;

#define FW   1024
#define NOUT 50
#define RPB  4      // rows (waves) per 256-thread block
#define CAP  320    // compacted-candidate capacity (n~203, +9 sigma safe)
#define SPL  5      // max slots per lane (CAP/64); hot path uses 4 (n<=256)

// ---- history ----
// r10: fused v_max_u32_dpp + s_nop NULL. r13: readlane x4 + s_max tree
// REGRESSED (VALU->SALU hazards). r14: -4 ops/iter -> -0.2us (25.69 BEST).
// r15: interleaved 2-rows/wave +1.6us. r16: proper per-block desync NULL.
// r17: pair-batched top-2 +2.3us. r18: sequential 2-rows/wave +4.0us --
// ANY drop from 4 waves/SIMD loses, op-preserving restructures lose,
// op removal ~nets zero. Cost models contradictory; kernel's own counters
// never visible (top-5 = harness memsets).
// r19: MEASUREMENT ROUND on r14-exact base. Run the (idempotent, LDS-read-
// only) NMS loop TWICE; sink run-1 via asm volatile (anti-DCE) + "memory"
// clobber between runs (anti-CSE). dur - 25.69 = true marginal loop cost,
// deciding whether the loop (~chains-sum) or the memory/prologue phase owns
// the unexplained ~10us.
#define DPP_UMAX_STEP(m, ctrl)                                                 \
  do {                                                                         \
    const u32 _t = (u32)__builtin_amdgcn_update_dpp(0, (int)(m), (ctrl),       \
                                                    0xf, 0xf, false);          \
    (m) = (m) > _t ? (m) : _t;                                                 \
  } while (0)
#define DPP_FMAX_STEP(m, ctrl)                                                 \
  do {                                                                         \
    const float _t = __uint_as_float((u32)__builtin_amdgcn_update_dpp(         \
        __float_as_int(m), __float_as_int(m), (ctrl), 0xf, 0xf, false));       \
    (m) = fmaxf((m), _t);                                                      \
  } while (0)
#define DPP_FMIN_STEP(m, ctrl)                                                 \
  do {                                                                         \
    const float _t = __uint_as_float((u32)__builtin_amdgcn_update_dpp(         \
        __float_as_int(m), __float_as_int(m), (ctrl), 0xf, 0xf, false));       \
    (m) = fminf((m), _t);                                                      \
  } while (0)
// inclusive add-scan step; row-masked bcast steps (round-7 lesson: 0xa/0xc)
#define DPP_SCAN_STEP(x, ctrl, rmask)                                          \
  do {                                                                         \
    const int _t = __builtin_amdgcn_update_dpp(0, (x), (ctrl), (rmask), 0xf,   \
                                               false);                         \
    (x) += _t;                                                                 \
  } while (0)

#define DPP_ALL6(OP, a)                                                        \
  OP(a, 0x111); OP(a, 0x112); OP(a, 0x114); OP(a, 0x118); OP(a, 0x142);        \
  OP(a, 0x143)

__device__ __forceinline__ u32 umax2(u32 a, u32 b) { return a > b ? a : b; }
__device__ __forceinline__ u32 umax3(u32 a, u32 b, u32 c) {
  return umax2(umax2(a, b), c);   // -> v_max3_u32
}

// r14 (kept): round-robin slot layout (slot k holds q = k*64+lane) so slot 4
// is empty whenever n <= 256 (true for essentially every row; n ~ 203+-13).
// Wave-uniform dispatch on the ACTUAL nc keeps the NS=5 path bit-exact.
template <int NS>
__device__ __forceinline__ u32 run_nms(const float2* __restrict__ kc, int nc,
                                       int lane, float dthresh) {
  u32 keys[NS];
  float cents[NS];
  {
    float2 sl[NS];
#pragma unroll
    for (int k = 0; k < NS; ++k) sl[k] = kc[k * 64 + lane];   // batch issue
#pragma unroll
    for (int k = 0; k < NS; ++k) {
      const int q2 = k * 64 + lane;
      keys[k]  = (q2 < nc) ? __float_as_uint(sl[k].x) : 0u;
      cents[k] = sl[k].y;          // garbage for q2>=nc harmless (key==0)
    }
  }

  u32 acckey = 0;        // lane j: winner key of output j (0 = none)
#pragma unroll
  for (int it = 0; it < NOUT; ++it) {
    u32 m = umax3(keys[0], keys[1], keys[2]);
#pragma unroll
    for (int k = 3; k < NS; ++k) m = umax2(m, keys[k]);
    DPP_UMAX_STEP(m, 0x111);
    DPP_UMAX_STEP(m, 0x112);
    DPP_UMAX_STEP(m, 0x114);
    DPP_UMAX_STEP(m, 0x118);
    DPP_UMAX_STEP(m, 0x142);
    DPP_UMAX_STEP(m, 0x143);
    const u32 best = (u32)__builtin_amdgcn_readlane((int)m, 63);   // SGPR

    // winner slot (scalar); clamp handles best==0 (keys all 0 -> harmless)
    const int qs  = 511 - (int)(best & 511u);
    const int qsc = qs < CAP ? qs : CAP - 1;
    const float sel_c = kc[qsc].y;      // uniform-addr ds_read broadcast
    // r9 POST-MORTEM (do not redo): register-resident sel_c REGRESSED +3.4us.

    // lane `it` keeps the winner key (it is a LITERAL here: v_cmp + cndmask)
    acckey = (lane == it) ? best : acckey;

    // suppress |cent - sel_c| <= dthresh (includes self -> progress)
#pragma unroll
    for (int k = 0; k < NS; ++k) {
      keys[k] = (fabsf(cents[k] - sel_c) <= dthresh) ? 0u : keys[k];
    }
  }
  return acckey;
}

__global__ __launch_bounds__(256, 4) void nms1d_kernel(
    const float* __restrict__ logits,
    const float* __restrict__ delta,
    const int* __restrict__ iw_p,
    float* __restrict__ out_pos,   // [B,50,2]
    float* __restrict__ out_sc)    // [B,50]
{
  const int wave = threadIdx.x >> 6;
  const int lane = threadIdx.x & 63;
  const int b = blockIdx.x * RPB + wave;

  // per-wave SoA slots + 1 dump slot (branchless scatter target).
  __shared__ float2 s_kc[RPB][CAP + 1];
  __shared__ float2 s_pp[RPB][CAP + 1];
  float2* __restrict__ kc = s_kc[wave];
  float2* __restrict__ pp = s_pp[wave];

  const float hi = (float)(*iw_p) - 1.0f;   // img_width - 1

  const float* __restrict__ lrow = logits + (size_t)b * FW;
  const float* __restrict__ drow = delta  + (size_t)b * FW * 2;

  // ---- batch-issue ALL global loads upfront (one latency exposure).
  float4 xl0 = *(const float4*)(lrow + lane * 16 + 0);
  float4 xl1 = *(const float4*)(lrow + lane * 16 + 4);
  float4 xl2 = *(const float4*)(lrow + lane * 16 + 8);
  float4 xl3 = *(const float4*)(lrow + lane * 16 + 12);
  float4 dA0 = *(const float4*)(drow + lane * 32 + 0);
  float4 dB0 = *(const float4*)(drow + lane * 32 + 4);
  float4 dA1 = *(const float4*)(drow + lane * 32 + 8);
  float4 dB1 = *(const float4*)(drow + lane * 32 + 12);
  float4 dA2 = *(const float4*)(drow + lane * 32 + 16);
  float4 dB2 = *(const float4*)(drow + lane * 32 + 20);
  float4 dA3 = *(const float4*)(drow + lane * 32 + 24);
  float4 dB3 = *(const float4*)(drow + lane * 32 + 28);

  // ---- pass 1: sigmoid + per-lane valid count (lane owns f = lane*16+e) ----
  float sc[16];
  int v = 0;
  const float4 xls[4] = {xl0, xl1, xl2, xl3};
#pragma unroll
  for (int c = 0; c < 4; ++c) {
    const float xs[4] = {xls[c].x, xls[c].y, xls[c].z, xls[c].w};
#pragma unroll
    for (int j = 0; j < 4; ++j) {
      const float s = 1.0f / (1.0f + expf(-xs[j]));   // frozen: bit-matched ref
      sc[c * 4 + j] = s;
      v += (s >= 0.7f) ? 1 : 0;
    }
  }

  // inclusive prefix sum over lanes via DPP (canonical masked scan, proven r8)
  int incl = v;
  DPP_SCAN_STEP(incl, 0x111, 0xf);   // row_shr:1
  DPP_SCAN_STEP(incl, 0x112, 0xf);   // row_shr:2
  DPP_SCAN_STEP(incl, 0x114, 0xf);   // row_shr:4
  DPP_SCAN_STEP(incl, 0x118, 0xf);   // row_shr:8
  DPP_SCAN_STEP(incl, 0x142, 0xa);   // row_bcast:15 -> rows 1,3 only
  DPP_SCAN_STEP(incl, 0x143, 0xc);   // row_bcast:31 -> rows 2,3 only
  const int base = incl - v;
  const int n = __builtin_amdgcn_readlane(incl, 63);

  // ---- pass 2: positions/centers, BRANCHLESS compacted scatter, vmin/vmax --
  float vmin = INFINITY, vmax = -INFINITY;
  int q = base;
  const float4 dAs[4] = {dA0, dA1, dA2, dA3};
  const float4 dBs[4] = {dB0, dB1, dB2, dB3};
#pragma unroll
  for (int c = 0; c < 4; ++c) {
    const float dx[4] = {dAs[c].x, dAs[c].z, dBs[c].x, dBs[c].z};
    const float dy[4] = {dAs[c].y, dAs[c].w, dBs[c].y, dBs[c].w};
#pragma unroll
    for (int j = 0; j < 4; ++j) {
      const int e = c * 4 + j;
      const int f = lane * 16 + e;
      const float center = (float)f * 16.0f + 8.0f;   // (f+0.5)*16, exact
      float p0 = dx[j] * 16.0f + center;              // frozen: bit-matched ref
      float p1 = dy[j] * 16.0f + center;
      p0 = fminf(fmaxf(p0, 0.0f), hi);
      p1 = fminf(fmaxf(p1, 0.0f), hi);
      const float cc = (p0 + p1) * 0.5f;
      const float s = sc[e];
      const bool valid = (s >= 0.7f);
      vmin = valid ? fminf(vmin, cc) : vmin;          // cndmask, no exec write
      vmax = valid ? fmaxf(vmax, cc) : vmax;
      // branchless scatter: invalid (or overflow) elements hit dump slot CAP
      const int qd = (valid && q < CAP) ? q : CAP;
      // u32 key: s in [0.7,1] -> bits-diff fits 23 bits; <<9 | (511-q)
      // exact order w/ first-index tie-break (lower q = lower f).
      const u32 key = ((__float_as_uint(s) - 0x3F333333u) << 9) | (u32)(511 - q);
      kc[qd] = make_float2(__uint_as_float(key), cc);
      pp[qd] = make_float2(p0, p1);
      q += valid ? 1 : 0;
    }
  }

  // wave min/max via DPP (old=self identity; exact). Lane 63 holds the result.
  DPP_ALL6(DPP_FMIN_STEP, vmin);
  DPP_ALL6(DPP_FMAX_STEP, vmax);
  const float dt_part = (0.55f * (vmax - vmin)) / ((float)incl - 1.0f);
  const float dthresh = __uint_as_float(
      (u32)__builtin_amdgcn_readlane(__float_as_int(dt_part), 63));
  // n==1 -> NaN -> suppresses nothing (matches ref); n>=2 -> >=0 -> self-suppress

  const int nc = n < CAP ? n : CAP;

  // ---- r19 PROBE: extra (idempotent) loop pass, sunk. run_nms only READS
  // LDS, so this does not perturb correctness. Sink defeats DCE; the
  // "memory" clobber defeats CSE of the two identical pure-LDS-read calls.
  {
    u32 probe;
    if (nc <= 256) probe = run_nms<4>(kc, nc, lane, dthresh);
    else           probe = run_nms<5>(kc, nc, lane, dthresh);
    asm volatile("" :: "v"(probe) : "memory");
  }

  // ---- greedy NMS (the real one): wave-uniform slot-count dispatch ----
  u32 acckey;
  if (nc <= 256) acckey = run_nms<4>(kc, nc, lane, dthresh);   // hot: ~always
  else           acckey = run_nms<5>(kc, nc, lane, dthresh);   // cold, exact

  // ---- epilogue: decode acckey, fetch p0/p1, single coalesced write ----
  if (lane < NOUT) {
    float p0 = 0.0f, p1 = 0.0f, s = 0.0f;
    if (acckey != 0u) {
      const int qw = 511 - (int)(acckey & 511u);    // valid -> qw < CAP
      const float2 sl = pp[qw];
      p0 = sl.x;
      p1 = sl.y;
      s  = __uint_as_float((acckey >> 9) + 0x3F333333u);   // exact score bits
    }
    float* __restrict__ orow_p = out_pos + (size_t)b * NOUT * 2;
    float* __restrict__ orow_s = out_sc  + (size_t)b * NOUT;
    *(float2*)(orow_p + lane * 2) = make_float2(p0, p1);
    orow_s[lane] = s;
  }
}

extern "C" void kernel_launch(void* const* d_in, const int* in_sizes, int n_in,
                              void* d_out, int out_size, void* d_ws, size_t ws_size,
                              hipStream_t stream) {
  const float* logits = (const float*)d_in[0];
  const float* delta  = (const float*)d_in[1];
  const int*   iw     = (const int*)d_in[2];
  const int B = in_sizes[0] / FW;            // 4096
  float* out_pos = (float*)d_out;                         // B*50*2
  float* out_sc  = (float*)d_out + (size_t)B * NOUT * 2;  // B*50
  nms1d_kernel<<<(B + RPB - 1) / RPB, RPB * 64, 0, stream>>>(logits, delta, iw, out_pos, out_sc);
}

// Round 12
// 26.292 us; speedup vs baseline: 1.3391x; 1.3391x over previous
//
#include <hip/hip_runtime.h>
#include <stdint.h>

typedef unsigned int u32;

#define FW   1024
#define NOUT 50
#define RPB  4      // rows (waves) per 256-thread block
#define CAP  320    // compacted-candidate capacity (n~203, +9 sigma safe)
#define SPL  5      // max slots per lane (CAP/64); hot path uses 4 (n<=256)

// ---- history ----
// r10 NULL, r13 +1.3, r14 BEST 25.69, r15 +1.6, r16 NULL, r17 +2.3, r18 +4.0.
// r19 PROBE: doubled NMS loop -> dur 35.21 => loop marginal = 9.5us.
//   DECOMPOSITION: loop 9.5 / non-loop 16.2. Loop is ~460cy/iter-window
//   (~2x pure issue -- reasonable). The anomaly is the NON-LOOP 16.2us:
//   mem floor ~7.7 + prologue-issue ~2 + epilogue ~0.5 + launch ~1 => ~5-6us
//   unattributed. r20 PROBE: double the PROLOGUE (idempotent: pure reg math
//   + identical LDS rewrites) to split prologue-compute vs memory-phase.
//   P = dur - 25.69. P small (~2-3) => memory phase ~13-14us vs 7.7 floor
//   => r21 stages loads coalesced via LDS. P large (~5-8) => prologue owns
//   it; expf frozen => near honest floor.
#define DPP_UMAX_STEP(m, ctrl)                                                 \
  do {                                                                         \
    const u32 _t = (u32)__builtin_amdgcn_update_dpp(0, (int)(m), (ctrl),       \
                                                    0xf, 0xf, false);          \
    (m) = (m) > _t ? (m) : _t;                                                 \
  } while (0)
#define DPP_FMAX_STEP(m, ctrl)                                                 \
  do {                                                                         \
    const float _t = __uint_as_float((u32)__builtin_amdgcn_update_dpp(         \
        __float_as_int(m), __float_as_int(m), (ctrl), 0xf, 0xf, false));       \
    (m) = fmaxf((m), _t);                                                      \
  } while (0)
#define DPP_FMIN_STEP(m, ctrl)                                                 \
  do {                                                                         \
    const float _t = __uint_as_float((u32)__builtin_amdgcn_update_dpp(         \
        __float_as_int(m), __float_as_int(m), (ctrl), 0xf, 0xf, false));       \
    (m) = fminf((m), _t);                                                      \
  } while (0)
// inclusive add-scan step; row-masked bcast steps (round-7 lesson: 0xa/0xc)
#define DPP_SCAN_STEP(x, ctrl, rmask)                                          \
  do {                                                                         \
    const int _t = __builtin_amdgcn_update_dpp(0, (x), (ctrl), (rmask), 0xf,   \
                                               false);                         \
    (x) += _t;                                                                 \
  } while (0)

#define DPP_ALL6(OP, a)                                                        \
  OP(a, 0x111); OP(a, 0x112); OP(a, 0x114); OP(a, 0x118); OP(a, 0x142);        \
  OP(a, 0x143)

__device__ __forceinline__ u32 umax2(u32 a, u32 b) { return a > b ? a : b; }
__device__ __forceinline__ u32 umax3(u32 a, u32 b, u32 c) {
  return umax2(umax2(a, b), c);   // -> v_max3_u32
}

struct RowData {
  float4 xl[4];   // logits
  float4 da[4];   // delta even-pairs
  float4 db[4];   // delta odd-pairs
};

// pass1 (sigmoid+count+scan) + pass2 (positions, branchless compacted
// scatter, vmin/vmax) + dthresh. FROZEN r8/r14 content, bit-matched ref.
// IDEMPOTENT: pure register math + rewrites of identical values to the
// same LDS slots -> safe to run twice (r20 probe).
__device__ __forceinline__ void prep_row(const RowData& d, float2* __restrict__ kc,
                                         float2* __restrict__ pp, int lane,
                                         float hi, float& dthresh_o, int& n_o) {
  float sc[16];
  int v = 0;
#pragma unroll
  for (int c = 0; c < 4; ++c) {
    const float xs[4] = {d.xl[c].x, d.xl[c].y, d.xl[c].z, d.xl[c].w};
#pragma unroll
    for (int j = 0; j < 4; ++j) {
      const float s = 1.0f / (1.0f + expf(-xs[j]));   // frozen: bit-matched ref
      sc[c * 4 + j] = s;
      v += (s >= 0.7f) ? 1 : 0;
    }
  }

  // inclusive prefix sum over lanes via DPP (canonical masked scan, proven r8)
  int incl = v;
  DPP_SCAN_STEP(incl, 0x111, 0xf);   // row_shr:1
  DPP_SCAN_STEP(incl, 0x112, 0xf);   // row_shr:2
  DPP_SCAN_STEP(incl, 0x114, 0xf);   // row_shr:4
  DPP_SCAN_STEP(incl, 0x118, 0xf);   // row_shr:8
  DPP_SCAN_STEP(incl, 0x142, 0xa);   // row_bcast:15 -> rows 1,3 only
  DPP_SCAN_STEP(incl, 0x143, 0xc);   // row_bcast:31 -> rows 2,3 only
  const int base = incl - v;
  const int n = __builtin_amdgcn_readlane(incl, 63);

  float vmin = INFINITY, vmax = -INFINITY;
  int q = base;
#pragma unroll
  for (int c = 0; c < 4; ++c) {
    const float dx[4] = {d.da[c].x, d.da[c].z, d.db[c].x, d.db[c].z};
    const float dy[4] = {d.da[c].y, d.da[c].w, d.db[c].y, d.db[c].w};
#pragma unroll
    for (int j = 0; j < 4; ++j) {
      const int e = c * 4 + j;
      const int f = lane * 16 + e;
      const float center = (float)f * 16.0f + 8.0f;   // (f+0.5)*16, exact
      float p0 = dx[j] * 16.0f + center;              // frozen: bit-matched ref
      float p1 = dy[j] * 16.0f + center;
      p0 = fminf(fmaxf(p0, 0.0f), hi);
      p1 = fminf(fmaxf(p1, 0.0f), hi);
      const float cc = (p0 + p1) * 0.5f;
      const float s = sc[e];
      const bool valid = (s >= 0.7f);
      vmin = valid ? fminf(vmin, cc) : vmin;          // cndmask, no exec write
      vmax = valid ? fmaxf(vmax, cc) : vmax;
      // branchless scatter: invalid (or overflow) elements hit dump slot CAP
      const int qd = (valid && q < CAP) ? q : CAP;
      // u32 key: s in [0.7,1] -> bits-diff fits 23 bits; <<9 | (511-q)
      // exact order w/ first-index tie-break (lower q = lower f).
      const u32 key = ((__float_as_uint(s) - 0x3F333333u) << 9) | (u32)(511 - q);
      kc[qd] = make_float2(__uint_as_float(key), cc);
      pp[qd] = make_float2(p0, p1);
      q += valid ? 1 : 0;
    }
  }

  // wave min/max via DPP (old=self identity; exact). Lane 63 holds the result.
  DPP_ALL6(DPP_FMIN_STEP, vmin);
  DPP_ALL6(DPP_FMAX_STEP, vmax);
  const float dt_part = (0.55f * (vmax - vmin)) / ((float)incl - 1.0f);
  dthresh_o = __uint_as_float(
      (u32)__builtin_amdgcn_readlane(__float_as_int(dt_part), 63));
  // n==1 -> NaN -> suppresses nothing (matches ref); n>=2 -> self-suppress
  n_o = n;
}

// r14 (kept, UNTOUCHED): round-robin slots; 4-slot hot path (n<=256, ~always);
// NS=5 bit-exact cold path via wave-uniform dispatch on actual nc.
template <int NS>
__device__ __forceinline__ u32 run_nms(const float2* __restrict__ kc, int nc,
                                       int lane, float dthresh) {
  u32 keys[NS];
  float cents[NS];
  {
    float2 sl[NS];
#pragma unroll
    for (int k = 0; k < NS; ++k) sl[k] = kc[k * 64 + lane];   // batch issue
#pragma unroll
    for (int k = 0; k < NS; ++k) {
      const int q2 = k * 64 + lane;
      keys[k]  = (q2 < nc) ? __float_as_uint(sl[k].x) : 0u;
      cents[k] = sl[k].y;          // garbage for q2>=nc harmless (key==0)
    }
  }

  u32 acckey = 0;        // lane j: winner key of output j (0 = none)
#pragma unroll
  for (int it = 0; it < NOUT; ++it) {
    u32 m = umax3(keys[0], keys[1], keys[2]);
#pragma unroll
    for (int k = 3; k < NS; ++k) m = umax2(m, keys[k]);
    DPP_UMAX_STEP(m, 0x111);
    DPP_UMAX_STEP(m, 0x112);
    DPP_UMAX_STEP(m, 0x114);
    DPP_UMAX_STEP(m, 0x118);
    DPP_UMAX_STEP(m, 0x142);
    DPP_UMAX_STEP(m, 0x143);
    const u32 best = (u32)__builtin_amdgcn_readlane((int)m, 63);   // SGPR

    // winner slot (scalar); clamp handles best==0 (keys all 0 -> harmless)
    const int qs  = 511 - (int)(best & 511u);
    const int qsc = qs < CAP ? qs : CAP - 1;
    const float sel_c = kc[qsc].y;      // uniform-addr ds_read broadcast
    // r9 POST-MORTEM (do not redo): register-resident sel_c REGRESSED +3.4us.

    // lane `it` keeps the winner key (it is a LITERAL here: v_cmp + cndmask)
    acckey = (lane == it) ? best : acckey;

    // suppress |cent - sel_c| <= dthresh (includes self -> progress)
#pragma unroll
    for (int k = 0; k < NS; ++k) {
      keys[k] = (fabsf(cents[k] - sel_c) <= dthresh) ? 0u : keys[k];
    }
  }
  return acckey;
}

__global__ __launch_bounds__(256, 4) void nms1d_kernel(
    const float* __restrict__ logits,
    const float* __restrict__ delta,
    const int* __restrict__ iw_p,
    float* __restrict__ out_pos,   // [B,50,2]
    float* __restrict__ out_sc)    // [B,50]
{
  const int wave = threadIdx.x >> 6;
  const int lane = threadIdx.x & 63;
  const int b = blockIdx.x * RPB + wave;

  // per-wave SoA slots + 1 dump slot (branchless scatter target).
  __shared__ float2 s_kc[RPB][CAP + 1];
  __shared__ float2 s_pp[RPB][CAP + 1];
  float2* __restrict__ kc = s_kc[wave];
  float2* __restrict__ pp = s_pp[wave];

  const float hi = (float)(*iw_p) - 1.0f;   // img_width - 1

  // ---- batch-issue ALL global loads upfront (one latency exposure).
  RowData A;
  {
    const float* __restrict__ lrow = logits + (size_t)b * FW;
    const float* __restrict__ drow = delta  + (size_t)b * FW * 2;
#pragma unroll
    for (int c = 0; c < 4; ++c)
      A.xl[c] = *(const float4*)(lrow + lane * 16 + 4 * c);
#pragma unroll
    for (int c = 0; c < 4; ++c) {
      A.da[c] = *(const float4*)(drow + lane * 32 + 8 * c);
      A.db[c] = *(const float4*)(drow + lane * 32 + 8 * c + 4);
    }
  }

  // ---- r20 PROBE: run the prologue TWICE. First call sunk (anti-DCE) with
  // a "memory" clobber (anti-CSE). Second call's outputs drive the real
  // path. Writes identical bytes to identical LDS slots -> idempotent.
  {
    float dt_probe; int n_probe;
    prep_row(A, kc, pp, lane, hi, dt_probe, n_probe);
    asm volatile("" :: "v"(__float_as_uint(dt_probe)), "v"(n_probe) : "memory");
  }

  float dthresh; int n;
  prep_row(A, kc, pp, lane, hi, dthresh, n);

  // ---- greedy NMS: 50 iters, wave-uniform slot-count dispatch ----
  const int nc = n < CAP ? n : CAP;
  u32 acckey;
  if (nc <= 256) acckey = run_nms<4>(kc, nc, lane, dthresh);   // hot: ~always
  else           acckey = run_nms<5>(kc, nc, lane, dthresh);   // cold, exact

  // ---- epilogue: decode acckey, fetch p0/p1, single coalesced write ----
  if (lane < NOUT) {
    float p0 = 0.0f, p1 = 0.0f, s = 0.0f;
    if (acckey != 0u) {
      const int qw = 511 - (int)(acckey & 511u);    // valid -> qw < CAP
      const float2 sl = pp[qw];
      p0 = sl.x;
      p1 = sl.y;
      s  = __uint_as_float((acckey >> 9) + 0x3F333333u);   // exact score bits
    }
    float* __restrict__ orow_p = out_pos + (size_t)b * NOUT * 2;
    float* __restrict__ orow_s = out_sc  + (size_t)b * NOUT;
    *(float2*)(orow_p + lane * 2) = make_float2(p0, p1);
    orow_s[lane] = s;
  }
}

extern "C" void kernel_launch(void* const* d_in, const int* in_sizes, int n_in,
                              void* d_out, int out_size, void* d_ws, size_t ws_size,
                              hipStream_t stream) {
  const float* logits = (const float*)d_in[0];
  const float* delta  = (const float*)d_in[1];
  const int*   iw     = (const int*)d_in[2];
  const int B = in_sizes[0] / FW;            // 4096
  float* out_pos = (float*)d_out;                         // B*50*2
  float* out_sc  = (float*)d_out + (size_t)B * NOUT * 2;  // B*50
  nms1d_kernel<<<(B + RPB - 1) / RPB, RPB * 64, 0, stream>>>(logits, delta, iw, out_pos, out_sc);
}

// Round 13
// 24.663 us; speedup vs baseline: 1.4276x; 1.0661x over previous
//
#include <hip/hip_runtime.h>
#include <stdint.h>

typedef unsigned int u32;

#define FW   1024
#define NOUT 50
#define RPB  4      // rows (waves) per 256-thread block
#define CAP  320    // compacted-candidate capacity (n~203, +9 sigma safe)
#define SPL  5      // max slots per lane (CAP/64); hot path uses 4 (n<=256)

// ---- history ----
// r10 NULL, r13 +1.3, r14 BEST 25.69, r15 +1.6, r16 NULL, r17 +2.3, r18 +4.0.
// r19 PROBE: loop marginal = 9.5us. r20 PROBE: prologue marginal = 0.6us.
// DECOMPOSITION: loop 9.5 / prologue 0.6 / epilogue+launch ~1.5 /
// MEMORY PHASE ~14us vs 7.7us float4-copy floor (~3.4 TB/s effective).
// Cause hypothesis: STRIDED loads. Old ownership f=lane*16+e made logits
// loads lane-stride 64B (4KB span, 32 lines/inst) and delta loads lane-
// stride 128B (8KB span, 64 lines/inst) -- ~640 line-requests per wave-row
// vs 96 ideal. r21: chunk-of-2 ownership f = g*128+lane*2+j -> logits 8x
// dwordx2 and delta 8x dwordx4, ALL perfectly lane-contiguous. Prefix scan
// becomes 8 per-chunk scans done as 2 byte-packed DPP scans (counts<=2/lane,
// totals<=128<256 -> no byte overflow). q stays strictly f-ordered ->
// bit-exact tie-break. run_nms/epilogue UNTOUCHED.
#define DPP_UMAX_STEP(m, ctrl)                                                 \
  do {                                                                         \
    const u32 _t = (u32)__builtin_amdgcn_update_dpp(0, (int)(m), (ctrl),       \
                                                    0xf, 0xf, false);          \
    (m) = (m) > _t ? (m) : _t;                                                 \
  } while (0)
#define DPP_FMAX_STEP(m, ctrl)                                                 \
  do {                                                                         \
    const float _t = __uint_as_float((u32)__builtin_amdgcn_update_dpp(         \
        __float_as_int(m), __float_as_int(m), (ctrl), 0xf, 0xf, false));       \
    (m) = fmaxf((m), _t);                                                      \
  } while (0)
#define DPP_FMIN_STEP(m, ctrl)                                                 \
  do {                                                                         \
    const float _t = __uint_as_float((u32)__builtin_amdgcn_update_dpp(         \
        __float_as_int(m), __float_as_int(m), (ctrl), 0xf, 0xf, false));       \
    (m) = fminf((m), _t);                                                      \
  } while (0)
// inclusive add-scan step; row-masked bcast steps (round-7 lesson: 0xa/0xc)
#define DPP_SCAN_STEP(x, ctrl, rmask)                                          \
  do {                                                                         \
    const int _t = __builtin_amdgcn_update_dpp(0, (x), (ctrl), (rmask), 0xf,   \
                                               false);                         \
    (x) += _t;                                                                 \
  } while (0)

#define DPP_ALL6(OP, a)                                                        \
  OP(a, 0x111); OP(a, 0x112); OP(a, 0x114); OP(a, 0x118); OP(a, 0x142);        \
  OP(a, 0x143)

__device__ __forceinline__ u32 umax2(u32 a, u32 b) { return a > b ? a : b; }
__device__ __forceinline__ u32 umax3(u32 a, u32 b, u32 c) {
  return umax2(umax2(a, b), c);   // -> v_max3_u32
}

// r14 (kept, UNTOUCHED): round-robin slots; 4-slot hot path (n<=256, ~always);
// NS=5 bit-exact cold path via wave-uniform dispatch on actual nc.
template <int NS>
__device__ __forceinline__ u32 run_nms(const float2* __restrict__ kc, int nc,
                                       int lane, float dthresh) {
  u32 keys[NS];
  float cents[NS];
  {
    float2 sl[NS];
#pragma unroll
    for (int k = 0; k < NS; ++k) sl[k] = kc[k * 64 + lane];   // batch issue
#pragma unroll
    for (int k = 0; k < NS; ++k) {
      const int q2 = k * 64 + lane;
      keys[k]  = (q2 < nc) ? __float_as_uint(sl[k].x) : 0u;
      cents[k] = sl[k].y;          // garbage for q2>=nc harmless (key==0)
    }
  }

  u32 acckey = 0;        // lane j: winner key of output j (0 = none)
#pragma unroll
  for (int it = 0; it < NOUT; ++it) {
    u32 m = umax3(keys[0], keys[1], keys[2]);
#pragma unroll
    for (int k = 3; k < NS; ++k) m = umax2(m, keys[k]);
    DPP_UMAX_STEP(m, 0x111);
    DPP_UMAX_STEP(m, 0x112);
    DPP_UMAX_STEP(m, 0x114);
    DPP_UMAX_STEP(m, 0x118);
    DPP_UMAX_STEP(m, 0x142);
    DPP_UMAX_STEP(m, 0x143);
    const u32 best = (u32)__builtin_amdgcn_readlane((int)m, 63);   // SGPR

    // winner slot (scalar); clamp handles best==0 (keys all 0 -> harmless)
    const int qs  = 511 - (int)(best & 511u);
    const int qsc = qs < CAP ? qs : CAP - 1;
    const float sel_c = kc[qsc].y;      // uniform-addr ds_read broadcast
    // r9 POST-MORTEM (do not redo): register-resident sel_c REGRESSED +3.4us.

    // lane `it` keeps the winner key (it is a LITERAL here: v_cmp + cndmask)
    acckey = (lane == it) ? best : acckey;

    // suppress |cent - sel_c| <= dthresh (includes self -> progress)
#pragma unroll
    for (int k = 0; k < NS; ++k) {
      keys[k] = (fabsf(cents[k] - sel_c) <= dthresh) ? 0u : keys[k];
    }
  }
  return acckey;
}

__global__ __launch_bounds__(256, 4) void nms1d_kernel(
    const float* __restrict__ logits,
    const float* __restrict__ delta,
    const int* __restrict__ iw_p,
    float* __restrict__ out_pos,   // [B,50,2]
    float* __restrict__ out_sc)    // [B,50]
{
  const int wave = threadIdx.x >> 6;
  const int lane = threadIdx.x & 63;
  const int b = blockIdx.x * RPB + wave;

  // per-wave SoA slots + 1 dump slot (branchless scatter target).
  __shared__ float2 s_kc[RPB][CAP + 1];
  __shared__ float2 s_pp[RPB][CAP + 1];
  float2* __restrict__ kc = s_kc[wave];
  float2* __restrict__ pp = s_pp[wave];

  const float hi = (float)(*iw_p) - 1.0f;   // img_width - 1

  const float* __restrict__ lrow = logits + (size_t)b * FW;
  const float* __restrict__ drow = delta  + (size_t)b * FW * 2;

  // ---- batch-issue ALL global loads upfront -- FULLY COALESCED (r21).
  // lane owns positions f = g*128 + lane*2 + {0,1}:
  //   logits: 8x dwordx2, byte off g*512 + lane*8  (contiguous 512B/inst)
  //   delta:  8x dwordx4, byte off g*4096 + lane*16 (contiguous 1KB/inst)
  float2 lg[8];
  float4 dl[8];
#pragma unroll
  for (int g = 0; g < 8; ++g)
    lg[g] = *(const float2*)(lrow + g * 128 + lane * 2);
#pragma unroll
  for (int g = 0; g < 8; ++g)
    dl[g] = *(const float4*)(drow + g * 256 + lane * 4);

  // ---- pass 1: sigmoid + per-chunk counts packed into 2 byte-words ----
  float sc[16];
  u32 pk0 = 0, pk1 = 0;
#pragma unroll
  for (int g = 0; g < 8; ++g) {
    const float s0 = 1.0f / (1.0f + expf(-lg[g].x));   // frozen: bit-matched
    const float s1 = 1.0f / (1.0f + expf(-lg[g].y));
    sc[2 * g]     = s0;
    sc[2 * g + 1] = s1;
    const u32 cnt = (s0 >= 0.7f ? 1u : 0u) + (s1 >= 0.7f ? 1u : 0u);
    if (g < 4) pk0 += cnt << (8 * g);
    else       pk1 += cnt << (8 * (g - 4));
  }

  // 8 independent prefix sums via 2 byte-packed DPP scans (proven r8 form;
  // byte fields can't overflow: per-chunk total <= 128 < 256).
  int i0 = (int)pk0, i1 = (int)pk1;
  DPP_SCAN_STEP(i0, 0x111, 0xf); DPP_SCAN_STEP(i1, 0x111, 0xf);
  DPP_SCAN_STEP(i0, 0x112, 0xf); DPP_SCAN_STEP(i1, 0x112, 0xf);
  DPP_SCAN_STEP(i0, 0x114, 0xf); DPP_SCAN_STEP(i1, 0x114, 0xf);
  DPP_SCAN_STEP(i0, 0x118, 0xf); DPP_SCAN_STEP(i1, 0x118, 0xf);
  DPP_SCAN_STEP(i0, 0x142, 0xa); DPP_SCAN_STEP(i1, 0x142, 0xa);
  DPP_SCAN_STEP(i0, 0x143, 0xc); DPP_SCAN_STEP(i1, 0x143, 0xc);
  const u32 e0 = (u32)i0 - pk0;   // exclusive packed, chunks 0-3
  const u32 e1 = (u32)i1 - pk1;   // exclusive packed, chunks 4-7
  const u32 t0 = (u32)__builtin_amdgcn_readlane(i0, 63);
  const u32 t1 = (u32)__builtin_amdgcn_readlane(i1, 63);

  // chunk bases (wave-uniform scalar running sum); n = grand total
  u32 cb[8];
  u32 run = 0;
#pragma unroll
  for (int g = 0; g < 8; ++g) {
    cb[g] = run;
    run += ((g < 4 ? t0 : t1) >> (8 * (g & 3))) & 0xFFu;
  }
  const int n = (int)run;

  // ---- pass 2: positions/centers, BRANCHLESS compacted scatter, vmin/vmax --
  // chunk-major, lane-major, j-major => q strictly f-ordered (exact
  // tie-break, same as r14's lane*16+e ordering semantics).
  float vmin = INFINITY, vmax = -INFINITY;
#pragma unroll
  for (int g = 0; g < 8; ++g) {
    int q = (int)(cb[g] + (((g < 4 ? e0 : e1) >> (8 * (g & 3))) & 0xFFu));
    const float dx[2] = {dl[g].x, dl[g].z};
    const float dy[2] = {dl[g].y, dl[g].w};
#pragma unroll
    for (int j = 0; j < 2; ++j) {
      const int e = 2 * g + j;
      const int f = g * 128 + lane * 2 + j;
      const float center = (float)f * 16.0f + 8.0f;   // (f+0.5)*16, exact
      float p0 = dx[j] * 16.0f + center;              // frozen: bit-matched ref
      float p1 = dy[j] * 16.0f + center;
      p0 = fminf(fmaxf(p0, 0.0f), hi);
      p1 = fminf(fmaxf(p1, 0.0f), hi);
      const float cc = (p0 + p1) * 0.5f;
      const float s = sc[e];
      const bool valid = (s >= 0.7f);
      vmin = valid ? fminf(vmin, cc) : vmin;          // cndmask, no exec write
      vmax = valid ? fmaxf(vmax, cc) : vmax;
      // branchless scatter: invalid (or overflow) elements hit dump slot CAP
      const int qd = (valid && q < CAP) ? q : CAP;
      // u32 key: s in [0.7,1] -> bits-diff fits 23 bits; <<9 | (511-q)
      // exact order w/ first-index tie-break (lower q = lower f).
      const u32 key = ((__float_as_uint(s) - 0x3F333333u) << 9) | (u32)(511 - q);
      kc[qd] = make_float2(__uint_as_float(key), cc);
      pp[qd] = make_float2(p0, p1);
      q += valid ? 1 : 0;
    }
  }

  // wave min/max via DPP (old=self identity; exact). Lane 63 holds the result.
  DPP_ALL6(DPP_FMIN_STEP, vmin);
  DPP_ALL6(DPP_FMAX_STEP, vmax);
  const float dt_part = (0.55f * (vmax - vmin)) / ((float)n - 1.0f);
  const float dthresh = __uint_as_float(
      (u32)__builtin_amdgcn_readlane(__float_as_int(dt_part), 63));
  // n==1 -> 0/0 = NaN -> suppresses nothing (matches ref); n>=2 -> >=0

  // ---- greedy NMS: 50 iters, wave-uniform slot-count dispatch ----
  const int nc = n < CAP ? n : CAP;
  u32 acckey;
  if (nc <= 256) acckey = run_nms<4>(kc, nc, lane, dthresh);   // hot: ~always
  else           acckey = run_nms<5>(kc, nc, lane, dthresh);   // cold, exact

  // ---- epilogue: decode acckey, fetch p0/p1, single coalesced write ----
  if (lane < NOUT) {
    float p0 = 0.0f, p1 = 0.0f, s = 0.0f;
    if (acckey != 0u) {
      const int qw = 511 - (int)(acckey & 511u);    // valid -> qw < CAP
      const float2 sl = pp[qw];
      p0 = sl.x;
      p1 = sl.y;
      s  = __uint_as_float((acckey >> 9) + 0x3F333333u);   // exact score bits
    }
    float* __restrict__ orow_p = out_pos + (size_t)b * NOUT * 2;
    float* __restrict__ orow_s = out_sc  + (size_t)b * NOUT;
    *(float2*)(orow_p + lane * 2) = make_float2(p0, p1);
    orow_s[lane] = s;
  }
}

extern "C" void kernel_launch(void* const* d_in, const int* in_sizes, int n_in,
                              void* d_out, int out_size, void* d_ws, size_t ws_size,
                              hipStream_t stream) {
  const float* logits = (const float*)d_in[0];
  const float* delta  = (const float*)d_in[1];
  const int*   iw     = (const int*)d_in[2];
  const int B = in_sizes[0] / FW;            // 4096
  float* out_pos = (float*)d_out;                         // B*50*2
  float* out_sc  = (float*)d_out + (size_t)B * NOUT * 2;  // B*50
  nms1d_kernel<<<(B + RPB - 1) / RPB, RPB * 64, 0, stream>>>(logits, delta, iw, out_pos, out_sc);
}